// Round 21
// baseline (57.497 us; speedup 1.0000x reference)
//
#include <hip/hip_runtime.h>
#include <hip/hip_bf16.h>

typedef __attribute__((ext_vector_type(8))) short bf16x8;
typedef __attribute__((ext_vector_type(16))) float f32x16;

#define DHEAD 64
#define L_SEQ 2048
#define QSCALE (0.125f * 1.44269504088896340736f)

// ws layout:
//  [4KB, 4KB+1MB)   ml float2[512][2][128]
//  [4KB+1MB, ~9.4MB) h=1 bf16 partial O [512][128][64]
//  [10MB, 18MB)     Kb  bf16 row-major [32][2048][64]
//  [18MB, 26MB)     Vt  bf16 transposed [32][64][2048]
#define WS_ML_OFF   4096
#define WS_PART_OFF (4096 + 512 * 2 * 128 * 8)
#define WS_KB_OFF   ((size_t)10 * 1024 * 1024)
#define WS_VT_OFF   ((size_t)18 * 1024 * 1024)
#define WS_NEED_B   ((size_t)WS_PART_OFF + (size_t)512 * 128 * 64 * 2)
#define WS_NEED_A   ((size_t)26 * 1024 * 1024)

union U4S8 { uint4 u; bf16x8 s; };

__device__ __forceinline__ unsigned pk2(float a, float b) {
    unsigned r;
    asm("v_cvt_pk_bf16_f32 %0, %1, %2" : "=v"(r) : "v"(a), "v"(b));
    return r;
}
__device__ __forceinline__ float bfrt(float x) {
    return __uint_as_float(pk2(x, x) << 16);
}
__device__ __forceinline__ float bf2f(unsigned short u) {
    return __uint_as_float((unsigned)u << 16);
}
__device__ __forceinline__ float fexp2(float x) {
#if __has_builtin(__builtin_amdgcn_exp2f)
    return __builtin_amdgcn_exp2f(x);
#else
    return __expf(x * 0.69314718055994530942f);
#endif
}

// r20-proven cross-half reduction (builtin owns regalloc + hazard nops).
#if __has_builtin(__builtin_amdgcn_permlane32_swap)
__device__ __forceinline__ float xhalf_max(float x) {
    const unsigned u = __float_as_uint(x);
    const auto r = __builtin_amdgcn_permlane32_swap(u, u, false, false);
    return fmaxf(__uint_as_float(r[0]), __uint_as_float(r[1]));
}
__device__ __forceinline__ float xhalf_sum(float x) {
    const unsigned u = __float_as_uint(x);
    const auto r = __builtin_amdgcn_permlane32_swap(u, u, false, false);
    return __uint_as_float(r[0]) + __uint_as_float(r[1]);
}
#else
__device__ __forceinline__ float xhalf_max(float x) { return fmaxf(x, __shfl_xor(x, 32)); }
__device__ __forceinline__ float xhalf_sum(float x) { return x + __shfl_xor(x, 32); }
#endif

#define MAX16(P) fmaxf(fmaxf(fmaxf(fmaxf(P[0],P[1]),fmaxf(P[2],P[3])),          \
                             fmaxf(fmaxf(P[4],P[5]),fmaxf(P[6],P[7]))),         \
                       fmaxf(fmaxf(fmaxf(P[8],P[9]),fmaxf(P[10],P[11])),        \
                             fmaxf(fmaxf(P[12],P[13]),fmaxf(P[14],P[15]))))
#define SUM16(P) ((((P[0]+P[1])+(P[2]+P[3]))+((P[4]+P[5])+(P[6]+P[7])))         \
                + (((P[8]+P[9])+(P[10]+P[11]))+((P[12]+P[13])+(P[14]+P[15]))))

// ---- pre-pass: K f32 -> bf16 row-major ----
__global__ __launch_bounds__(256)
void conv_k(const float* __restrict__ K, unsigned short* __restrict__ Kb) {
    const size_t i = ((size_t)blockIdx.x * 256 + threadIdx.x) * 8;
    const float4 a = *(const float4*)(K + i);
    const float4 b = *(const float4*)(K + i + 4);
    *(uint4*)(Kb + i) = make_uint4(pk2(a.x, a.y), pk2(a.z, a.w),
                                   pk2(b.x, b.y), pk2(b.z, b.w));
}

// ---- pre-pass: V f32 -> bf16 TRANSPOSED Vt[bh][d][seq] (LDS-tiled) ----
__global__ __launch_bounds__(256)
void conv_vt(const float* __restrict__ V, unsigned short* __restrict__ Vt) {
    __shared__ unsigned short lt[64][72];   // 64 seq x 64 d, pad 8
    const int bh = blockIdx.x >> 5, sb = blockIdx.x & 31;
    const int t = threadIdx.x, r = t >> 2, c0 = (t & 3) * 16;
    const float* Vp = V + ((size_t)bh * L_SEQ + sb * 64 + r) * DHEAD + c0;
    const float4 a = ((const float4*)Vp)[0], b = ((const float4*)Vp)[1];
    const float4 cc = ((const float4*)Vp)[2], d = ((const float4*)Vp)[3];
    *(uint4*)&lt[r][c0]     = make_uint4(pk2(a.x, a.y), pk2(a.z, a.w),
                                         pk2(b.x, b.y), pk2(b.z, b.w));
    *(uint4*)&lt[r][c0 + 8] = make_uint4(pk2(cc.x, cc.y), pk2(cc.z, cc.w),
                                         pk2(d.x, d.y), pk2(d.z, d.w));
    __syncthreads();
    const int dd = t >> 2, s0 = (t & 3) * 16;
    unsigned short tmp[16];
    #pragma unroll
    for (int j = 0; j < 16; ++j) tmp[j] = lt[s0 + j][dd];
    unsigned u[8];
    #pragma unroll
    for (int j = 0; j < 8; ++j)
        u[j] = (unsigned)tmp[2 * j] | ((unsigned)tmp[2 * j + 1] << 16);
    unsigned short* o = Vt + ((size_t)bh * 64 + dd) * L_SEQ + sb * 64 + s0;
    ((uint4*)o)[0] = make_uint4(u[0], u[1], u[2], u[3]);
    ((uint4*)o)[1] = make_uint4(u[4], u[5], u[6], u[7]);
}

// Body = r13/r20 (best, 51.8us). Schedule: 1024 jobs = 32bh x 16T x 2 parities.
// PRE=1: staging from pre-converted bf16 (Kb row-major, Vt transposed) — every
// fragment-slot's 16B is CONTIGUOUS in global -> 8 uint4 loads + 8 ds_writes
// per thread, zero pk2, half the bytes. PRE=0: f32 staging (r20).
// LDS chunk map (all ds ops chunk_base + lane*16, conflict-free):
//  K chunk kb*4+kc, slot l: K[kb*32+(l&31)][kc*16+8*(l>>5)+j]
//  V chunk kv*2+dt, slot l: V[kv*16+8*(l>>5)+j][dt*32+(l&31)]

template<int SPLIT, int PRE>
__global__ __launch_bounds__(256, 3)
void fattn_kernel(const float* __restrict__ Qg, const float* __restrict__ Kg,
                  const float* __restrict__ Vg, float* __restrict__ Og,
                  char* __restrict__ wsBase) {
    __shared__ uint4 sK4[16][64];
    __shared__ uint4 sV4[16][64];

    const int tid  = threadIdx.x;
    const int lane = tid & 63;
    const int w    = tid >> 6;
    const int hi   = lane >> 5;
    const int c    = lane & 31;

    const int id  = blockIdx.x;
    const int bh  = (id & 7) + 8 * ((id >> 3) & 3);   // 4 bh per XCD

    int T, h, kt0, kstep, d;
    if (SPLIT) {
        const int k31 = 31 - (id >> 5);   // LPT
        T = k31 >> 1;
        h = 1 - (k31 & 1);
        d = (T + 2 - h) >> 1;
        if (d == 0) return;
        kt0 = h; kstep = 2;
    } else {
        const int u_ = id >> 5;
        T = (u_ < 8) ? (15 - u_) : (u_ - 8);
        h = 0; d = T + 1; kt0 = 0; kstep = 1;
    }

    const size_t base = (size_t)bh * L_SEQ * DHEAD;
    const int q0w = T * 128 + w * 32;

    // ---- Q fragments (B-operand), scale folded ----
    bf16x8 qf[4];
    {
        const float* Qrow = Qg + base + (size_t)(q0w + c) * DHEAD;
        #pragma unroll
        for (int kc = 0; kc < 4; ++kc) {
            float4 aa = *(const float4*)(Qrow + kc * 16 + hi * 8);
            float4 bb = *(const float4*)(Qrow + kc * 16 + hi * 8 + 4);
            U4S8 t;
            t.u = make_uint4(pk2(aa.x * QSCALE, aa.y * QSCALE),
                             pk2(aa.z * QSCALE, aa.w * QSCALE),
                             pk2(bb.x * QSCALE, bb.y * QSCALE),
                             pk2(bb.z * QSCALE, bb.w * QSCALE));
            qf[kc] = t.s;
        }
    }

    // ---- staging bases ----
    const float* Kpb = Kg + base + (size_t)(32 * w + c) * DHEAD + 32 * hi;
    const float* Vpb = Vg + base + (size_t)(32 * w + 16 * hi) * DHEAD + c;
    const unsigned short* KbB = (const unsigned short*)(wsBase + WS_KB_OFF)
                              + base + (size_t)(32 * w + c) * DHEAD + 32 * hi;
    const unsigned short* VtB = (const unsigned short*)(wsBase + WS_VT_OFF)
                              + (size_t)bh * 64 * L_SEQ + (2 * w + hi) * 16;

    auto stage_K = [&](int kt) {
        if (PRE) {
            const unsigned short* Kt = KbB + (size_t)kt * 128 * DHEAD;
            const uint4 k00 = *(const uint4*)(Kt + 0);
            const uint4 k01 = *(const uint4*)(Kt + 8);
            const uint4 k10 = *(const uint4*)(Kt + 16);
            const uint4 k11 = *(const uint4*)(Kt + 24);
            sK4[w * 4 + 2 * hi][c]          = k00;
            sK4[w * 4 + 2 * hi][32 + c]     = k01;
            sK4[w * 4 + 2 * hi + 1][c]      = k10;
            sK4[w * 4 + 2 * hi + 1][32 + c] = k11;
        } else {
            float4 rk[8];
            const float* Kp = Kpb + (size_t)kt * 128 * DHEAD;
            #pragma unroll
            for (int t = 0; t < 8; ++t) rk[t] = *(const float4*)(Kp + 4 * t);
            #pragma unroll
            for (int q = 0; q < 2; ++q)
                #pragma unroll
                for (int hh = 0; hh < 2; ++hh) {
                    const float4 r0 = rk[4 * q + 2 * hh], r1 = rk[4 * q + 2 * hh + 1];
                    sK4[w * 4 + 2 * hi + q][hh * 32 + c] =
                        make_uint4(pk2(r0.x, r0.y), pk2(r0.z, r0.w),
                                   pk2(r1.x, r1.y), pk2(r1.z, r1.w));
                }
        }
    };
    auto stage_V = [&](int kt) {
        if (PRE) {
            const unsigned short* Vk = VtB + (size_t)kt * 128;
            const unsigned short* Vr0 = Vk + (size_t)c * L_SEQ;
            const unsigned short* Vr1 = Vk + (size_t)(32 + c) * L_SEQ;
            const uint4 v00 = *(const uint4*)(Vr0 + 0);
            const uint4 v01 = *(const uint4*)(Vr0 + 8);
            const uint4 v10 = *(const uint4*)(Vr1 + 0);
            const uint4 v11 = *(const uint4*)(Vr1 + 8);
            sV4[(2 * w + hi) * 2][c]          = v00;
            sV4[(2 * w + hi) * 2][32 + c]     = v01;
            sV4[(2 * w + hi) * 2 + 1][c]      = v10;
            sV4[(2 * w + hi) * 2 + 1][32 + c] = v11;
        } else {
            float rv[32];
            const float* Vp = Vpb + (size_t)kt * 128 * DHEAD;
            #pragma unroll
            for (int j = 0; j < 16; ++j) {
                rv[j]      = Vp[j * DHEAD];
                rv[16 + j] = Vp[j * DHEAD + 32];
            }
            #pragma unroll
            for (int dt = 0; dt < 2; ++dt)
                #pragma unroll
                for (int hh = 0; hh < 2; ++hh) {
                    const int b = 16 * dt + 8 * hh;
                    sV4[(2 * w + hi) * 2 + dt][hh * 32 + c] =
                        make_uint4(pk2(rv[b + 0], rv[b + 1]), pk2(rv[b + 2], rv[b + 3]),
                                   pk2(rv[b + 4], rv[b + 5]), pk2(rv[b + 6], rv[b + 7]));
                }
        }
    };

    f32x16 o0 = {0,0,0,0,0,0,0,0,0,0,0,0,0,0,0,0};
    f32x16 o1 = o0;
    float m_r = -1e30f, l_r = 0.f;

    stage_K(kt0);
    stage_V(kt0);
    __syncthreads();

    for (int j = 0; j < d; ++j) {
        const int  kt   = kt0 + j * kstep;
        const bool pf   = (j + 1 < d);
        const bool diag = (kt == T);

        #pragma unroll
        for (int sub = 0; sub < 2; ++sub) {
            const int lim = diag ? (w + 1 - 2 * sub) : 2;
            const int nkb = lim < 0 ? 0 : (lim > 2 ? 2 : lim);
            if (nkb > 0) {
                float p[2][16];

                __builtin_amdgcn_s_setprio(1);
                #pragma unroll
                for (int i = 0; i < 2; ++i) {
                    if (i < nkb) {
                        f32x16 s = {0,0,0,0,0,0,0,0,0,0,0,0,0,0,0,0};
                        #pragma unroll
                        for (int kc = 0; kc < 4; ++kc) {
                            U4S8 t; t.u = sK4[(2 * sub + i) * 4 + kc][lane];
                            s = __builtin_amdgcn_mfma_f32_32x32x16_bf16(t.s, qf[kc], s, 0, 0, 0);
                        }
                        #pragma unroll
                        for (int r = 0; r < 16; ++r) p[i][r] = s[r];
                    }
                }
                __builtin_amdgcn_s_setprio(0);

                #pragma unroll
                for (int i = 0; i < 2; ++i) {
                    if (diag && (2 * sub + i) == w) {
                        #pragma unroll
                        for (int r = 0; r < 16; ++r) {
                            const int kk = (r & 3) + 8 * (r >> 2) + 4 * hi;
                            if (kk > c) p[i][r] = -1e30f;
                        }
                    }
                }

                float mx = MAX16(p[0]);
                if (nkb > 1) mx = fmaxf(mx, MAX16(p[1]));
                mx = xhalf_max(mx);

                if (__any(mx > m_r + 8.f)) {
                    const float mn    = fmaxf(m_r, mx);
                    const float alpha = fexp2(m_r - mn);
                    m_r  = mn;
                    l_r *= alpha;
                    #pragma unroll
                    for (int r = 0; r < 16; ++r) {
                        const float ab = __shfl(alpha, (r & 3) + 8 * (r >> 2) + 4 * hi);
                        o0[r] *= ab; o1[r] *= ab;
                    }
                }

                #pragma unroll
                for (int i = 0; i < 2; ++i) {
                    if (i < nkb) {
                        #pragma unroll
                        for (int r = 0; r < 16; ++r) p[i][r] = fexp2(p[i][r] - m_r);
                    }
                }
                float rs = SUM16(p[0]);
                if (nkb > 1) rs += SUM16(p[1]);
                rs = xhalf_sum(rs);
                l_r += rs;

                __builtin_amdgcn_s_setprio(1);
                #pragma unroll
                for (int kcl = 0; kcl < 4; ++kcl) {
                    if (kcl < 2 * nkb) {
                        const int i = kcl >> 1, bs = (kcl & 1) * 8;
                        unsigned a0 = pk2(p[i][bs + 0], p[i][bs + 1]);
                        unsigned a1 = pk2(p[i][bs + 2], p[i][bs + 3]);
                        unsigned b0 = pk2(p[i][bs + 4], p[i][bs + 5]);
                        unsigned b1 = pk2(p[i][bs + 6], p[i][bs + 7]);
                        asm("v_permlane32_swap_b32 %0, %1" : "+v"(a0), "+v"(b0));
                        asm("v_permlane32_swap_b32 %0, %1" : "+v"(a1), "+v"(b1));
                        U4S8 t;
                        t.u = make_uint4(a0, a1, b0, b1);
                        const int kv = 4 * sub + kcl;
                        U4S8 tv0; tv0.u = sV4[kv * 2][lane];
                        o0 = __builtin_amdgcn_mfma_f32_32x32x16_bf16(t.s, tv0.s, o0, 0, 0, 0);
                        U4S8 tv1; tv1.u = sV4[kv * 2 + 1][lane];
                        o1 = __builtin_amdgcn_mfma_f32_32x32x16_bf16(t.s, tv1.s, o1, 0, 0, 0);
                    }
                }
                __builtin_amdgcn_s_setprio(0);
            }
        }

        if (pf) {
            __syncthreads();
            stage_K(kt + kstep);
            stage_V(kt + kstep);
            __syncthreads();
        }
    }

    float* Op = Og + base;

    if (!SPLIT || T == 0) {
        const float linv = 1.f / l_r;
        #pragma unroll
        for (int r = 0; r < 16; ++r) {
            const int   cr  = (r & 3) + 8 * (r >> 2) + 4 * hi;
            const float lb  = __shfl(linv, cr);
            const int   row = q0w + cr;
            Op[(size_t)row * DHEAD + c]      = o0[r] * lb;
            Op[(size_t)row * DHEAD + 32 + c] = o1[r] * lb;
        }
        return;
    }

    const int f = bh * 16 + T;
    float2* ml = (float2*)(wsBase + WS_ML_OFF);
    if (hi == 0) ml[((size_t)f * 2 + h) * 128 + w * 32 + c] = make_float2(m_r, l_r);
    if (h == 0) {
        #pragma unroll
        for (int r = 0; r < 16; ++r) {
            const int cr  = (r & 3) + 8 * (r >> 2) + 4 * hi;
            const int row = q0w + cr;
            Op[(size_t)row * DHEAD + c]      = bfrt(o0[r]);
            Op[(size_t)row * DHEAD + 32 + c] = bfrt(o1[r]);
        }
    } else {
        unsigned short* mp = (unsigned short*)(wsBase + WS_PART_OFF) + (size_t)f * 128 * 64;
        #pragma unroll
        for (int r = 0; r < 16; ++r) {
            const int cr   = (r & 3) + 8 * (r >> 2) + 4 * hi;
            const int lrow = w * 32 + cr;
            mp[lrow * 64 + c]      = (unsigned short)pk2(o0[r], o0[r]);
            mp[lrow * 64 + 32 + c] = (unsigned short)pk2(o1[r], o1[r]);
        }
    }
}

__global__ __launch_bounds__(256)
void merge_kernel(float* __restrict__ Og, const char* __restrict__ wsBase) {
    const int blk = blockIdx.x;
    const int bh = blk >> 4, T = blk & 15;
    if (T == 0) return;
    const int f = bh * 16 + T;

    const float2* ml = (const float2*)(wsBase + WS_ML_OFF);
    const unsigned short* part =
        (const unsigned short*)(wsBase + WS_PART_OFF) + (size_t)f * 128 * 64;
    float* Op = Og + ((size_t)bh * L_SEQ + (size_t)T * 128) * DHEAD;

    __shared__ float sA0[128], sA1[128], sLi[128];
    const int t = threadIdx.x;
    if (t < 128) {
        const float2 m0 = ml[((size_t)f * 2 + 0) * 128 + t];
        const float2 m1 = ml[((size_t)f * 2 + 1) * 128 + t];
        const float mM = fmaxf(m0.x, m1.x);
        const float a0 = fexp2(m0.x - mM);
        const float a1 = fexp2(m1.x - mM);
        sA0[t] = a0; sA1[t] = a1;
        sLi[t] = 1.f / (a0 * m0.y + a1 * m1.y);
    }
    __syncthreads();

    #pragma unroll
    for (int e = 0; e < 8; ++e) {
        const int idx4 = e * 256 + t;
        const int row  = idx4 >> 4;
        const int c4   = (idx4 & 15) * 4;
        const float a0 = sA0[row], a1 = sA1[row], li = sLi[row];
        float4 po = *(float4*)&Op[row * 64 + c4];
        const ushort4 u = *(const ushort4*)&part[row * 64 + c4];
        po.x = (a0 * po.x + a1 * bf2f(u.x)) * li;
        po.y = (a0 * po.y + a1 * bf2f(u.y)) * li;
        po.z = (a0 * po.z + a1 * bf2f(u.z)) * li;
        po.w = (a0 * po.w + a1 * bf2f(u.w)) * li;
        *(float4*)&Op[row * 64 + c4] = po;
    }
}

extern "C" void kernel_launch(void* const* d_in, const int* in_sizes, int n_in,
                              void* d_out, int out_size, void* d_ws, size_t ws_size,
                              hipStream_t stream) {
    const float* Q = (const float*)d_in[0];
    const float* K = (const float*)d_in[1];
    const float* V = (const float*)d_in[2];
    float* O = (float*)d_out;
    char* ws = (char*)d_ws;
    if (ws_size >= WS_NEED_A) {
        conv_k<<<dim3(2048), dim3(256), 0, stream>>>(K, (unsigned short*)(ws + WS_KB_OFF));
        conv_vt<<<dim3(1024), dim3(256), 0, stream>>>(V, (unsigned short*)(ws + WS_VT_OFF));
        fattn_kernel<1, 1><<<dim3(1024), dim3(256), 0, stream>>>(Q, K, V, O, ws);
        merge_kernel<<<dim3(512), dim3(256), 0, stream>>>(O, ws);
    } else if (ws_size >= WS_NEED_B) {
        fattn_kernel<1, 0><<<dim3(1024), dim3(256), 0, stream>>>(Q, K, V, O, ws);
        merge_kernel<<<dim3(512), dim3(256), 0, stream>>>(O, ws);
    } else {
        fattn_kernel<0, 0><<<dim3(512), dim3(256), 0, stream>>>(Q, K, V, O, ws);
    }
}

// Round 22
// 52.246 us; speedup vs baseline: 1.1005x; 1.1005x over previous
//
#include <hip/hip_runtime.h>
#include <hip/hip_bf16.h>

typedef __attribute__((ext_vector_type(8))) short bf16x8;
typedef __attribute__((ext_vector_type(4))) float f32x4;
typedef __attribute__((ext_vector_type(16))) float f32x16;

#define DHEAD 64
#define L_SEQ 2048
#define QSCALE (0.125f * 1.44269504088896340736f)

// ws layout: [4KB, 4KB+1MB) ml float2[512][2][128];
// [4KB+1MB, +8MB) h=1 bf16 partial O [512][128][64]
#define WS_ML_OFF   4096
#define WS_PART_OFF (4096 + 512 * 2 * 128 * 8)
#define WS_NEED     ((size_t)WS_PART_OFF + (size_t)512 * 128 * 64 * 2)

union U4S8 { uint4 u; bf16x8 s; };

__device__ __forceinline__ unsigned pk2(float a, float b) {
    unsigned r;
    asm("v_cvt_pk_bf16_f32 %0, %1, %2" : "=v"(r) : "v"(a), "v"(b));
    return r;
}
__device__ __forceinline__ float bfrt(float x) {
    return __uint_as_float(pk2(x, x) << 16);
}
__device__ __forceinline__ float bf2f(unsigned short u) {
    return __uint_as_float((unsigned)u << 16);
}
__device__ __forceinline__ float fexp2(float x) {
#if __has_builtin(__builtin_amdgcn_exp2f)
    return __builtin_amdgcn_exp2f(x);
#else
    return __expf(x * 0.69314718055994530942f);
#endif
}

// r20-proven cross-half reduction (builtin owns regalloc + hazard nops).
#if __has_builtin(__builtin_amdgcn_permlane32_swap)
__device__ __forceinline__ float xhalf_max(float x) {
    const unsigned u = __float_as_uint(x);
    const auto r = __builtin_amdgcn_permlane32_swap(u, u, false, false);
    return fmaxf(__uint_as_float(r[0]), __uint_as_float(r[1]));
}
__device__ __forceinline__ float xhalf_sum(float x) {
    const unsigned u = __float_as_uint(x);
    const auto r = __builtin_amdgcn_permlane32_swap(u, u, false, false);
    return __uint_as_float(r[0]) + __uint_as_float(r[1]);
}
#else
__device__ __forceinline__ float xhalf_max(float x) { return fmaxf(x, __shfl_xor(x, 32)); }
__device__ __forceinline__ float xhalf_sum(float x) { return x + __shfl_xor(x, 32); }
#endif

#define MAX16(P) fmaxf(fmaxf(fmaxf(fmaxf(P[0],P[1]),fmaxf(P[2],P[3])),          \
                             fmaxf(fmaxf(P[4],P[5]),fmaxf(P[6],P[7]))),         \
                       fmaxf(fmaxf(fmaxf(P[8],P[9]),fmaxf(P[10],P[11])),        \
                             fmaxf(fmaxf(P[12],P[13]),fmaxf(P[14],P[15]))))
#define SUM16(P) ((((P[0]+P[1])+(P[2]+P[3]))+((P[4]+P[5])+(P[6]+P[7])))         \
                + (((P[8]+P[9])+(P[10]+P[11]))+((P[12]+P[13])+(P[14]+P[15]))))

// Body = r20 (51.8us, passed) with ONE change (r21 lesson: staging instruction
// count was ~12us of fattn time; pre-pass cost more than it saved — so fix
// staging in-kernel): stage_V reassigned so each thread owns 8k x 4 consecutive
// d -> 8 coalesced dwordx4 loads (was 32 scalar dwords), 16 pk2 (identical
// values/rounding), 4 ds_write_b128. V writes accept ~8-way bank conflicts
// (slot%4 fixed per step); sV4 padded [16][65] rotates chunk bases; PV reads
// remain conflict-free (chunk_base + lane*16).
// LDS map: K chunk kb*4+kc, slot l: K[kb*32+(l&31)][kc*16+8*(l>>5)+j]
//          V chunk kv*2+dt, slot l: V[kv*16+8*(l>>5)+j][dt*32+(l&31)]

template<int SPLIT>
__global__ __launch_bounds__(256, 3)
void fattn_kernel(const float* __restrict__ Qg, const float* __restrict__ Kg,
                  const float* __restrict__ Vg, float* __restrict__ Og,
                  char* __restrict__ wsBase) {
    __shared__ uint4 sK4[16][64];
    __shared__ uint4 sV4[16][65];   // +1 slot pad: rotates chunk base banks

    const int tid  = threadIdx.x;
    const int lane = tid & 63;
    const int w    = tid >> 6;
    const int hi   = lane >> 5;
    const int c    = lane & 31;

    const int id  = blockIdx.x;
    const int bh  = (id & 7) + 8 * ((id >> 3) & 3);   // 4 bh per XCD

    int T, h, kt0, kstep, d;
    if (SPLIT) {
        const int k31 = 31 - (id >> 5);   // LPT
        T = k31 >> 1;
        h = 1 - (k31 & 1);
        d = (T + 2 - h) >> 1;
        if (d == 0) return;
        kt0 = h; kstep = 2;
    } else {
        const int u_ = id >> 5;
        T = (u_ < 8) ? (15 - u_) : (u_ - 8);
        h = 0; d = T + 1; kt0 = 0; kstep = 1;
    }

    const size_t base = (size_t)bh * L_SEQ * DHEAD;
    const int q0w = T * 128 + w * 32;

    // ---- Q fragments (B-operand), scale folded ----
    bf16x8 qf[4];
    {
        const float* Qrow = Qg + base + (size_t)(q0w + c) * DHEAD;
        #pragma unroll
        for (int kc = 0; kc < 4; ++kc) {
            float4 aa = *(const float4*)(Qrow + kc * 16 + hi * 8);
            float4 bb = *(const float4*)(Qrow + kc * 16 + hi * 8 + 4);
            U4S8 t;
            t.u = make_uint4(pk2(aa.x * QSCALE, aa.y * QSCALE),
                             pk2(aa.z * QSCALE, aa.w * QSCALE),
                             pk2(bb.x * QSCALE, bb.y * QSCALE),
                             pk2(bb.z * QSCALE, bb.w * QSCALE));
            qf[kc] = t.s;
        }
    }

    // ---- staging bases ----
    const float* Kpb = Kg + base + (size_t)(32 * w + c) * DHEAD + 32 * hi;
    const int kg = tid >> 4;        // V: k-octet (k = kg*8 + j)
    const int dq = tid & 15;        // V: d-quad  (d = dq*4 + dd)
    const float* VpB = Vg + base + (size_t)(kg * 8) * DHEAD + dq * 4;

    auto stage_K = [&](int kt) {    // 8 dwordx4 + 16 pk2 + 4 writes (unchanged)
        float4 rk[8];
        const float* Kp = Kpb + (size_t)kt * 128 * DHEAD;
        #pragma unroll
        for (int t = 0; t < 8; ++t) rk[t] = *(const float4*)(Kp + 4 * t);
        #pragma unroll
        for (int q = 0; q < 2; ++q)
            #pragma unroll
            for (int hh = 0; hh < 2; ++hh) {
                const float4 r0 = rk[4 * q + 2 * hh], r1 = rk[4 * q + 2 * hh + 1];
                sK4[w * 4 + 2 * hi + q][hh * 32 + c] =
                    make_uint4(pk2(r0.x, r0.y), pk2(r0.z, r0.w),
                               pk2(r1.x, r1.y), pk2(r1.z, r1.w));
            }
    };
    auto stage_V = [&](int kt) {    // NEW: 8 coalesced dwordx4 (was 32 scalar)
        f32x4 rv4[8];
        const float* Vp = VpB + (size_t)kt * 128 * DHEAD;
        #pragma unroll
        for (int j = 0; j < 8; ++j) rv4[j] = *(const f32x4*)(Vp + j * DHEAD);
        #pragma unroll
        for (int dd = 0; dd < 4; ++dd) {        // compile-time indices only
            const int dv = dq * 4 + dd;
            const int ch = (kg >> 1) * 2 + (dv >> 5);
            const int sl = ((kg & 1) << 5) | (dv & 31);
            sV4[ch][sl] = make_uint4(pk2(rv4[0][dd], rv4[1][dd]),
                                     pk2(rv4[2][dd], rv4[3][dd]),
                                     pk2(rv4[4][dd], rv4[5][dd]),
                                     pk2(rv4[6][dd], rv4[7][dd]));
        }
    };

    f32x16 o0 = {0,0,0,0,0,0,0,0,0,0,0,0,0,0,0,0};
    f32x16 o1 = o0;
    float m_r = -1e30f, l_r = 0.f;

    stage_K(kt0);
    stage_V(kt0);
    __syncthreads();

    for (int j = 0; j < d; ++j) {
        const int  kt   = kt0 + j * kstep;
        const bool pf   = (j + 1 < d);
        const bool diag = (kt == T);

        #pragma unroll
        for (int sub = 0; sub < 2; ++sub) {
            const int lim = diag ? (w + 1 - 2 * sub) : 2;
            const int nkb = lim < 0 ? 0 : (lim > 2 ? 2 : lim);
            if (nkb > 0) {
                float p[2][16];

                __builtin_amdgcn_s_setprio(1);
                #pragma unroll
                for (int i = 0; i < 2; ++i) {
                    if (i < nkb) {
                        f32x16 s = {0,0,0,0,0,0,0,0,0,0,0,0,0,0,0,0};
                        #pragma unroll
                        for (int kc = 0; kc < 4; ++kc) {
                            U4S8 t; t.u = sK4[(2 * sub + i) * 4 + kc][lane];
                            s = __builtin_amdgcn_mfma_f32_32x32x16_bf16(t.s, qf[kc], s, 0, 0, 0);
                        }
                        #pragma unroll
                        for (int r = 0; r < 16; ++r) p[i][r] = s[r];
                    }
                }
                __builtin_amdgcn_s_setprio(0);

                #pragma unroll
                for (int i = 0; i < 2; ++i) {
                    if (diag && (2 * sub + i) == w) {
                        #pragma unroll
                        for (int r = 0; r < 16; ++r) {
                            const int kk = (r & 3) + 8 * (r >> 2) + 4 * hi;
                            if (kk > c) p[i][r] = -1e30f;
                        }
                    }
                }

                float mx = MAX16(p[0]);
                if (nkb > 1) mx = fmaxf(mx, MAX16(p[1]));
                mx = xhalf_max(mx);

                if (__any(mx > m_r + 8.f)) {
                    const float mn    = fmaxf(m_r, mx);
                    const float alpha = fexp2(m_r - mn);
                    m_r  = mn;
                    l_r *= alpha;
                    #pragma unroll
                    for (int r = 0; r < 16; ++r) {
                        const float ab = __shfl(alpha, (r & 3) + 8 * (r >> 2) + 4 * hi);
                        o0[r] *= ab; o1[r] *= ab;
                    }
                }

                #pragma unroll
                for (int i = 0; i < 2; ++i) {
                    if (i < nkb) {
                        #pragma unroll
                        for (int r = 0; r < 16; ++r) p[i][r] = fexp2(p[i][r] - m_r);
                    }
                }
                float rs = SUM16(p[0]);
                if (nkb > 1) rs += SUM16(p[1]);
                rs = xhalf_sum(rs);
                l_r += rs;

                __builtin_amdgcn_s_setprio(1);
                #pragma unroll
                for (int kcl = 0; kcl < 4; ++kcl) {
                    if (kcl < 2 * nkb) {
                        const int i = kcl >> 1, bs = (kcl & 1) * 8;
                        unsigned a0 = pk2(p[i][bs + 0], p[i][bs + 1]);
                        unsigned a1 = pk2(p[i][bs + 2], p[i][bs + 3]);
                        unsigned b0 = pk2(p[i][bs + 4], p[i][bs + 5]);
                        unsigned b1 = pk2(p[i][bs + 6], p[i][bs + 7]);
                        asm("v_permlane32_swap_b32 %0, %1" : "+v"(a0), "+v"(b0));
                        asm("v_permlane32_swap_b32 %0, %1" : "+v"(a1), "+v"(b1));
                        U4S8 t;
                        t.u = make_uint4(a0, a1, b0, b1);
                        const int kv = 4 * sub + kcl;
                        U4S8 tv0; tv0.u = sV4[kv * 2][lane];
                        o0 = __builtin_amdgcn_mfma_f32_32x32x16_bf16(t.s, tv0.s, o0, 0, 0, 0);
                        U4S8 tv1; tv1.u = sV4[kv * 2 + 1][lane];
                        o1 = __builtin_amdgcn_mfma_f32_32x32x16_bf16(t.s, tv1.s, o1, 0, 0, 0);
                    }
                }
                __builtin_amdgcn_s_setprio(0);
            }
        }

        if (pf) {
            __syncthreads();
            stage_K(kt + kstep);
            stage_V(kt + kstep);
            __syncthreads();
        }
    }

    float* Op = Og + base;

    if (!SPLIT || T == 0) {
        const float linv = 1.f / l_r;
        #pragma unroll
        for (int r = 0; r < 16; ++r) {
            const int   cr  = (r & 3) + 8 * (r >> 2) + 4 * hi;
            const float lb  = __shfl(linv, cr);
            const int   row = q0w + cr;
            Op[(size_t)row * DHEAD + c]      = o0[r] * lb;
            Op[(size_t)row * DHEAD + 32 + c] = o1[r] * lb;
        }
        return;
    }

    const int f = bh * 16 + T;
    float2* ml = (float2*)(wsBase + WS_ML_OFF);
    if (hi == 0) ml[((size_t)f * 2 + h) * 128 + w * 32 + c] = make_float2(m_r, l_r);
    if (h == 0) {
        #pragma unroll
        for (int r = 0; r < 16; ++r) {
            const int cr  = (r & 3) + 8 * (r >> 2) + 4 * hi;
            const int row = q0w + cr;
            Op[(size_t)row * DHEAD + c]      = bfrt(o0[r]);
            Op[(size_t)row * DHEAD + 32 + c] = bfrt(o1[r]);
        }
    } else {
        unsigned short* mp = (unsigned short*)(wsBase + WS_PART_OFF) + (size_t)f * 128 * 64;
        #pragma unroll
        for (int r = 0; r < 16; ++r) {
            const int cr   = (r & 3) + 8 * (r >> 2) + 4 * hi;
            const int lrow = w * 32 + cr;
            mp[lrow * 64 + c]      = (unsigned short)pk2(o0[r], o0[r]);
            mp[lrow * 64 + 32 + c] = (unsigned short)pk2(o1[r], o1[r]);
        }
    }
}

// Streaming merge: one block per (bh,T), exact online-softmax combine.
__global__ __launch_bounds__(256)
void merge_kernel(float* __restrict__ Og, const char* __restrict__ wsBase) {
    const int blk = blockIdx.x;
    const int bh = blk >> 4, T = blk & 15;
    if (T == 0) return;
    const int f = bh * 16 + T;

    const float2* ml = (const float2*)(wsBase + WS_ML_OFF);
    const unsigned short* part =
        (const unsigned short*)(wsBase + WS_PART_OFF) + (size_t)f * 128 * 64;
    float* Op = Og + ((size_t)bh * L_SEQ + (size_t)T * 128) * DHEAD;

    __shared__ float sA0[128], sA1[128], sLi[128];
    const int t = threadIdx.x;
    if (t < 128) {
        const float2 m0 = ml[((size_t)f * 2 + 0) * 128 + t];
        const float2 m1 = ml[((size_t)f * 2 + 1) * 128 + t];
        const float mM = fmaxf(m0.x, m1.x);
        const float a0 = fexp2(m0.x - mM);
        const float a1 = fexp2(m1.x - mM);
        sA0[t] = a0; sA1[t] = a1;
        sLi[t] = 1.f / (a0 * m0.y + a1 * m1.y);
    }
    __syncthreads();

    #pragma unroll
    for (int e = 0; e < 8; ++e) {
        const int idx4 = e * 256 + t;
        const int row  = idx4 >> 4;
        const int c4   = (idx4 & 15) * 4;
        const float a0 = sA0[row], a1 = sA1[row], li = sLi[row];
        float4 po = *(float4*)&Op[row * 64 + c4];
        const ushort4 u = *(const ushort4*)&part[row * 64 + c4];
        po.x = (a0 * po.x + a1 * bf2f(u.x)) * li;
        po.y = (a0 * po.y + a1 * bf2f(u.y)) * li;
        po.z = (a0 * po.z + a1 * bf2f(u.z)) * li;
        po.w = (a0 * po.w + a1 * bf2f(u.w)) * li;
        *(float4*)&Op[row * 64 + c4] = po;
    }
}

extern "C" void kernel_launch(void* const* d_in, const int* in_sizes, int n_in,
                              void* d_out, int out_size, void* d_ws, size_t ws_size,
                              hipStream_t stream) {
    const float* Q = (const float*)d_in[0];
    const float* K = (const float*)d_in[1];
    const float* V = (const float*)d_in[2];
    float* O = (float*)d_out;
    if (ws_size >= WS_NEED) {
        fattn_kernel<1><<<dim3(1024), dim3(256), 0, stream>>>(Q, K, V, O, (char*)d_ws);
        merge_kernel<<<dim3(512), dim3(256), 0, stream>>>(O, (const char*)d_ws);
    } else {
        fattn_kernel<0><<<dim3(512), dim3(256), 0, stream>>>(Q, K, V, O, (char*)d_ws);
    }
}